// Round 7
// baseline (434.251 us; speedup 1.0000x reference)
//
#include <hip/hip_runtime.h>
#include <hip/hip_bf16.h>

// ---------- types ----------
using short8  = __attribute__((ext_vector_type(8))) short;
using ushort8 = __attribute__((ext_vector_type(8))) unsigned short;
using f32x4   = __attribute__((ext_vector_type(4))) float;

#define GLB(p)  ((const __attribute__((address_space(1))) void*)(p))
#define LDSP(p) ((__attribute__((address_space(3))) void*)(p))

static __device__ __forceinline__ unsigned short f2bf(float f) {
    union { float f; unsigned u; } v; v.f = f;
    unsigned u = v.u;
    u += 0x7fffu + ((u >> 16) & 1u);   // round-to-nearest-even
    return (unsigned short)(u >> 16);
}

// ---------- problem constants ----------
#define K_DIM 2048
#define N_DIM 2048
#define M_TOTAL 26112
#define N_GROUPS 8
#define NB_TASKS 64     // 8 kc x 8 B-stripes (256 n x 256 k transpose each)
#define NA_TASKS 816    // 8 kc x 102 A-panels (256 rows x 256 k each), kc-major
#define DONE_TGT 110u   // per-kc: 8 B + 102 A

// ctl layout in ws: ctl[0]=qheadB, ctl[1]=qheadA, ctl[2..9]=done[kc]

// ---------- sync helpers ----------
#define PBAR() __builtin_amdgcn_s_barrier()
#define LGKM0() asm volatile("s_waitcnt lgkmcnt(0)" ::: "memory")
#define VMC(n)  asm volatile("s_waitcnt vmcnt(" #n ")" ::: "memory")

static __device__ __forceinline__ void wait_done(const unsigned* d) {
    while (__hip_atomic_load(d, __ATOMIC_ACQUIRE, __HIP_MEMORY_SCOPE_AGENT) < DONE_TGT)
        __builtin_amdgcn_s_sleep(16);
}

// ---------- A-panel resolution & convert task ----------
static __device__ __forceinline__ const float* a_src(int idx,
        const float* A0, const float* A1, const float* A2, const float* A3,
        const float* A4, const float* A5, const float* A6, const float* A7, int* gr0) {
    if      (idx < 16) { *gr0 = 0;     return A0; }
    else if (idx < 24) { *gr0 = 4096;  return A1; }
    else if (idx < 28) { *gr0 = 6144;  return A2; }
    else if (idx < 60) { *gr0 = 7168;  return A3; }
    else if (idx < 62) { *gr0 = 15360; return A4; }
    else if (idx < 74) { *gr0 = 15872; return A5; }
    else if (idx < 98) { *gr0 = 18944; return A6; }
    else               { *gr0 = 25088; return A7; }
}

static __device__ void do_a_task(int idx, int akc, const float* src, int gr0,
                                 unsigned short* Acat, int tid) {
    long srow0 = (long)idx * 256 - gr0;
    int rl = tid >> 5, cc = (tid & 31) * 8;
#pragma unroll 4
    for (int p = 0; p < 16; ++p) {
        int r = p * 16 + rl;
        const float* s = src + (srow0 + r) * K_DIM + akc * 256 + cc;
        float4 x = *(const float4*)s;
        float4 y = *(const float4*)(s + 4);
        ushort8 o;
        o[0] = f2bf(x.x); o[1] = f2bf(x.y); o[2] = f2bf(x.z); o[3] = f2bf(x.w);
        o[4] = f2bf(y.x); o[5] = f2bf(y.y); o[6] = f2bf(y.z); o[7] = f2bf(y.w);
        *(ushort8*)(Acat + (long)(idx * 256 + r) * K_DIM + akc * 256 + cc) = o;
    }
}

// steal-or-wait until K-chunk kc is fully converted (block-uniform; deadlock-free:
// a blocked block converts the data it waits for itself)
static __device__ __attribute__((noinline)) void fill_chunk(int kc, unsigned* ctl,
        volatile int* ctl_s, unsigned short* Acat, int tid,
        const float* A0, const float* A1, const float* A2, const float* A3,
        const float* A4, const float* A5, const float* A6, const float* A7) {
    unsigned* qa   = ctl + 1;
    unsigned* done = ctl + 2;
    for (;;) {
        if (tid == 0) {
            int v;
            if (__hip_atomic_load(&done[kc], __ATOMIC_ACQUIRE,
                                  __HIP_MEMORY_SCOPE_AGENT) >= DONE_TGT)
                v = -1;                                   // chunk ready
            else {
                unsigned t = __hip_atomic_fetch_add(qa, 1u, __ATOMIC_RELAXED,
                                                    __HIP_MEMORY_SCOPE_AGENT);
                v = (t < NA_TASKS) ? (int)t : -2;          // task, or queue drained
            }
            ctl_s[0] = v;
        }
        __syncthreads();
        int T = ctl_s[0];
        if (T < 0) {
            __syncthreads();
            if (T == -2) wait_done(&done[kc]);            // stragglers finishing
            return;
        }
        int akc = T / 102, idx = T - akc * 102;
        int gr0; const float* src = a_src(idx, A0, A1, A2, A3, A4, A5, A6, A7, &gr0);
        do_a_task(idx, akc, src, gr0, Acat, tid);
        __syncthreads();
        if (tid == 0)
            __hip_atomic_fetch_add(&done[akc], 1u, __ATOMIC_RELEASE,
                                   __HIP_MEMORY_SCOPE_AGENT);
    }
}

// ---------- GEMM staging / MFMA macros (round-4 proven structure, verbatim) ----------
#define ST_A(BUF, H, L, TT)                                                        \
    __builtin_amdgcn_global_load_lds(                                              \
        GLB(aSt + (long)((H) * 128 + (L) * 64) * K_DIM + (TT) * 64),               \
        LDSP(lds + (BUF) * 32768 + (H) * 8192 + (L) * 4096 + w * 512), 16, 0, 0)
#define ST_B(BUF, H, L, TT)                                                        \
    __builtin_amdgcn_global_load_lds(                                              \
        GLB(bSt + (long)((H) * 128 + (L) * 64) * K_DIM + (TT) * 64),               \
        LDSP(lds + (BUF) * 32768 + 16384 + (H) * 8192 + (L) * 4096 + w * 512), 16, 0, 0)

#define MMQ(MH, NH, AV, BV)                                                        \
    _Pragma("unroll") for (int i = 0; i < 4; ++i)                                  \
    _Pragma("unroll") for (int j = 0; j < 2; ++j)                                  \
        acc[(MH) * 4 + i][(NH) * 2 + j] = __builtin_amdgcn_mfma_f32_16x16x32_bf16( \
            AV[i], BV[j], acc[(MH) * 4 + i][(NH) * 2 + j], 0, 0, 0);

#define TILE(BUF, T, DO1, DO2)                                                          \
    do {                                                                                \
        const unsigned short* pA = lds + (BUF) * 32768 + wm * 1024 + r16 * 64;          \
        const unsigned short* pB = lds + (BUF) * 32768 + 16384 + wn * 1024 + r16 * 64;  \
        short8 a0[4], a1[4], b00[2], b01[2], b10[2], b11[2];                            \
        /* ph1: read A-h0 + B-h0; stage A(T+1)-h1 -> buf^1; MFMA m0n0 */                \
        _Pragma("unroll") for (int i = 0; i < 4; ++i) {                                 \
            a0[i] = *(const short8*)(pA + i * 2048 + c0 * 8);                           \
            a1[i] = *(const short8*)(pA + i * 2048 + c1 * 8);                           \
        }                                                                               \
        _Pragma("unroll") for (int j = 0; j < 2; ++j) {                                 \
            b00[j] = *(const short8*)(pB + j * 4096 + c0 * 8);                          \
            b01[j] = *(const short8*)(pB + j * 4096 + c1 * 8);                          \
        }                                                                               \
        if (DO1) { ST_A((BUF) ^ 1, 1, 0, (T) + 1); ST_A((BUF) ^ 1, 1, 1, (T) + 1); }    \
        PBAR(); LGKM0();                                                                \
        __builtin_amdgcn_s_setprio(1); MMQ(0, 0, a0, b00); MMQ(0, 0, a1, b01);          \
        __builtin_amdgcn_s_setprio(0); PBAR();                                          \
        /* ph2: read B-h1; stage A(T+2)-h0 -> buf; MFMA m0n1 */                         \
        _Pragma("unroll") for (int j = 0; j < 2; ++j) {                                 \
            b10[j] = *(const short8*)(pB + 8192 + j * 4096 + c0 * 8);                   \
            b11[j] = *(const short8*)(pB + 8192 + j * 4096 + c1 * 8);                   \
        }                                                                               \
        if (DO2) { ST_A((BUF), 0, 0, (T) + 2); ST_A((BUF), 0, 1, (T) + 2); }            \
        PBAR(); LGKM0();                                                                \
        __builtin_amdgcn_s_setprio(1); MMQ(0, 1, a0, b10); MMQ(0, 1, a1, b11);          \
        __builtin_amdgcn_s_setprio(0); PBAR();                                          \
        /* ph3: read A-h1; stage B(T+2)-h0 -> buf; MFMA m1n0 */                         \
        _Pragma("unroll") for (int i = 0; i < 4; ++i) {                                 \
            a0[i] = *(const short8*)(pA + 8192 + i * 2048 + c0 * 8);                    \
            a1[i] = *(const short8*)(pA + 8192 + i * 2048 + c1 * 8);                    \
        }                                                                               \
        if (DO2) { ST_B((BUF), 0, 0, (T) + 2); ST_B((BUF), 0, 1, (T) + 2); }            \
        PBAR(); LGKM0();                                                                \
        __builtin_amdgcn_s_setprio(1); MMQ(1, 0, a0, b00); MMQ(1, 0, a1, b01);          \
        __builtin_amdgcn_s_setprio(0); PBAR();                                          \
        /* ph4: register-only; stage B(T+2)-h1 -> buf; MFMA m1n1 */                     \
        if (DO2) { ST_B((BUF), 1, 0, (T) + 2); ST_B((BUF), 1, 1, (T) + 2); }            \
        __builtin_amdgcn_s_setprio(1); MMQ(1, 1, a0, b10); MMQ(1, 1, a1, b11);          \
        __builtin_amdgcn_s_setprio(0);                                                  \
    } while (0)

// ---------- GEMM body (round-4 pipeline; WAIT adds steal-or-wait chunk gates) ----------
template <bool WAIT>
static __device__ __forceinline__ void gemm_body(unsigned short* __restrict__ Acat,
        const unsigned short* __restrict__ Bt, float* __restrict__ C,
        unsigned* __restrict__ ctl, volatile int* ctl_s, unsigned short* lds,
        int m0, int n0, int tid,
        const float* A0, const float* A1, const float* A2, const float* A3,
        const float* A4, const float* A5, const float* A6, const float* A7) {
    int l   = tid & 63;
    int w   = tid >> 6;
    int wm  = w >> 2, wn = w & 3;
    int r16 = l & 15, kq = l >> 4, x = l & 7;
    int c0  = kq ^ x;            // swizzled chunk, k-step 0
    int c1  = (4 + kq) ^ x;      // swizzled chunk, k-step 1
    int srow = tid >> 3;
    int sq   = (tid & 7) ^ (srow & 7);
    const unsigned short* aSt = Acat + (long)(m0 + srow) * K_DIM + sq * 8;
    const unsigned short* bSt = Bt   + (long)(n0 + srow) * K_DIM + sq * 8;

    f32x4 acc[8][4] = {};

    if (WAIT) fill_chunk(0, ctl, ctl_s, Acat, tid, A0, A1, A2, A3, A4, A5, A6, A7);

    // prologue: tile0 full (8) + tile1 A0,B0,B1 (6); wait tile0 (vmcnt 6)
    ST_A(0, 0, 0, 0); ST_A(0, 0, 1, 0); ST_A(0, 1, 0, 0); ST_A(0, 1, 1, 0);
    ST_B(0, 0, 0, 0); ST_B(0, 0, 1, 0); ST_B(0, 1, 0, 0); ST_B(0, 1, 1, 0);
    ST_A(1, 0, 0, 1); ST_A(1, 0, 1, 1);
    ST_B(1, 0, 0, 1); ST_B(1, 0, 1, 1); ST_B(1, 1, 0, 1); ST_B(1, 1, 1, 1);
    VMC(6); PBAR();

#pragma unroll 1
    for (int t = 0; t < 30; t += 2) {
        if (WAIT && (t & 3) == 2)
            fill_chunk((t + 2) >> 2, ctl, ctl_s, Acat, tid,
                       A0, A1, A2, A3, A4, A5, A6, A7);
        TILE(0, t, 1, 1);     VMC(6); PBAR();
        TILE(1, t + 1, 1, 1); VMC(6); PBAR();
    }
    TILE(0, 30, 1, 0); VMC(0); PBAR();
    TILE(1, 31, 0, 0);

    // epilogue: C/D layout col=lane&15, row=(lane>>4)*4+q
    int orow = m0 + wm * 16 + (l >> 4) * 4;
    int ocol = n0 + wn * 16 + (l & 15);
#pragma unroll
    for (int i = 0; i < 8; ++i)
#pragma unroll
        for (int j = 0; j < 4; ++j)
#pragma unroll
            for (int q = 0; q < 4; ++q)
                C[(long)(orow + i * 32 + q) * N_DIM + (ocol + j * 64)] = acc[i][j][q];
}

// ---------- fused kernel: work-steal convert + gated round-4 GEMM ----------
__global__ __launch_bounds__(512, 2) void fused_all(
        const float* __restrict__ A0, const float* __restrict__ A1,
        const float* __restrict__ A2, const float* __restrict__ A3,
        const float* __restrict__ A4, const float* __restrict__ A5,
        const float* __restrict__ A6, const float* __restrict__ A7,
        const float* __restrict__ B,
        unsigned short* __restrict__ Acat, unsigned short* __restrict__ Bt,
        unsigned* __restrict__ ctl, float* __restrict__ C) {
    __shared__ unsigned short lds[65536];   // 128 KiB GEMM double buffer / convert scratch
    __shared__ int ctl_s[2];
    int tid = threadIdx.x;

    // ---- phase 1: drain B-transpose queue (64 small tasks; uses lds, pre-GEMM) ----
    for (;;) {
        if (tid == 0) {
            unsigned t = __hip_atomic_fetch_add(&ctl[0], 1u, __ATOMIC_RELAXED,
                                                __HIP_MEMORY_SCOPE_AGENT);
            ctl_s[0] = (t < NB_TASKS) ? (int)t : -1;
        }
        __syncthreads();
        int T = ctl_s[0];
        if (T < 0) { __syncthreads(); break; }
        int kc = T >> 3, g = T & 7;        // kc-major
        float* ldsf = (float*)lds;
        int w8 = tid >> 6, l = tid & 63;
        for (int st = 0; st < 4; ++st) {
#pragma unroll
            for (int i = 0; i < 8; ++i) {
                int kr = i * 8 + w8;
                float4 v = *(const float4*)(B + (long)(kc * 256 + st * 64 + kr) * N_DIM +
                                            g * 256 + l * 4);
                *(float4*)(ldsf + kr * 260 + l * 4) = v;
            }
            __syncthreads();
            int n = tid >> 1, jo = (tid & 1) * 32;
            unsigned short* dst = Bt + (long)(g * 256 + n) * K_DIM + kc * 256 + st * 64 + jo;
#pragma unroll
            for (int jj = 0; jj < 4; ++jj) {
                ushort8 o;
#pragma unroll
                for (int q = 0; q < 8; ++q) o[q] = f2bf(ldsf[(jo + jj * 8 + q) * 260 + n]);
                *(ushort8*)(dst + jj * 8) = o;
            }
            __syncthreads();
        }
        if (tid == 0)
            __hip_atomic_fetch_add(&ctl[2 + kc], 1u, __ATOMIC_RELEASE,
                                   __HIP_MEMORY_SCOPE_AGENT);
        __syncthreads();
    }

    // ---- phase 2: block-uniform ready check (fast path = zero-overhead round-4) ----
    if (tid == 0) {
        int r = 1;
        for (int k = 0; k < 8; ++k)
            r &= (__hip_atomic_load(&ctl[2 + k], __ATOMIC_ACQUIRE,
                                    __HIP_MEMORY_SCOPE_AGENT) >= DONE_TGT) ? 1 : 0;
        ctl_s[1] = r;
    }
    __syncthreads();
    int ready = ctl_s[1];

    // ---- phase 3: GEMM tile (816 = 102 mtiles x 8 ntiles; bijective XCD swizzle) ----
    int wg  = blockIdx.x;
    int swz = (wg & 7) * 102 + (wg >> 3);
    int mt  = swz >> 3, nt = swz & 7;
    int m0  = mt * 256, n0 = nt * 256;

    if (ready)
        gemm_body<false>(Acat, Bt, C, ctl, ctl_s, lds, m0, n0, tid,
                         A0, A1, A2, A3, A4, A5, A6, A7);
    else
        gemm_body<true>(Acat, Bt, C, ctl, ctl_s, lds, m0, n0, tid,
                        A0, A1, A2, A3, A4, A5, A6, A7);
}

// ---------- fallback: correct (slow) fp32 tiled GEMM, used only if ws too small ----------
__global__ void naive_gemm_kernel(const float* __restrict__ A, const float* __restrict__ B,
                                  float* __restrict__ C, int M) {
    __shared__ float As[16][16];
    __shared__ float Bs[16][17];
    int tx = threadIdx.x, ty = threadIdx.y;
    int row = blockIdx.y * 16 + ty;
    int col = blockIdx.x * 16 + tx;
    float s = 0.f;
    for (int k0 = 0; k0 < K_DIM; k0 += 16) {
        As[ty][tx] = A[(long)row * K_DIM + k0 + tx];
        Bs[ty][tx] = B[(long)(k0 + ty) * N_DIM + col];
        __syncthreads();
#pragma unroll
        for (int t = 0; t < 16; ++t) s += As[ty][t] * Bs[t][tx];
        __syncthreads();
    }
    C[(long)row * N_DIM + col] = s;
}

// ---------- host launcher ----------
extern "C" void kernel_launch(void* const* d_in, const int* in_sizes, int n_in,
                              void* d_out, int out_size, void* d_ws, size_t ws_size,
                              hipStream_t stream) {
    static const int g_m[N_GROUPS]   = {4096, 2048, 1024, 8192, 512, 3072, 6144, 1024};
    static const int g_off[N_GROUPS] = {0, 4096, 6144, 7168, 15360, 15872, 18944, 25088};

    float* C = (float*)d_out;
    const size_t acat_elems = (size_t)M_TOTAL * K_DIM;
    const size_t bt_elems   = (size_t)N_DIM * K_DIM;
    const size_t need = (acat_elems + bt_elems) * 2 + 256;

    if (ws_size >= need) {
        unsigned short* Acat = (unsigned short*)d_ws;
        unsigned short* Bt   = Acat + acat_elems;
        unsigned* ctl        = (unsigned*)(Bt + bt_elems);

        hipMemsetAsync(ctl, 0, 64, stream);
        fused_all<<<(M_TOTAL / 256) * (N_DIM / 256), 512, 0, stream>>>(
            (const float*)d_in[0], (const float*)d_in[1], (const float*)d_in[2],
            (const float*)d_in[3], (const float*)d_in[4], (const float*)d_in[5],
            (const float*)d_in[6], (const float*)d_in[7], (const float*)d_in[8],
            Acat, Bt, ctl, C);
    } else {
        for (int g = 0; g < N_GROUPS; ++g)
            naive_gemm_kernel<<<dim3(N_DIM / 16, g_m[g] / 16), dim3(16, 16), 0, stream>>>(
                (const float*)d_in[g], (const float*)d_in[8], C + (size_t)g_off[g] * N_DIM,
                g_m[g]);
    }
}

// Round 8
// 282.022 us; speedup vs baseline: 1.5398x; 1.5398x over previous
//
#include <hip/hip_runtime.h>
#include <hip/hip_bf16.h>

// ---------- types ----------
using short8  = __attribute__((ext_vector_type(8))) short;
using ushort8 = __attribute__((ext_vector_type(8))) unsigned short;
using f32x4   = __attribute__((ext_vector_type(4))) float;

#define GLB(p)  ((const __attribute__((address_space(1))) void*)(p))
#define LDSP(p) ((__attribute__((address_space(3))) void*)(p))

static __device__ __forceinline__ unsigned short f2bf(float f) {
    union { float f; unsigned u; } v; v.f = f;
    unsigned u = v.u;
    u += 0x7fffu + ((u >> 16) & 1u);   // round-to-nearest-even
    return (unsigned short)(u >> 16);
}

// ---------- problem constants ----------
#define K_DIM 2048
#define N_DIM 2048
#define M_TOTAL 26112
#define N_GROUPS 8

// ---------- kernel 1: all A groups fp32 -> contiguous bf16 Acat ----------
__global__ __launch_bounds__(256) void cvt_a_all(
        const float* __restrict__ A0, const float* __restrict__ A1,
        const float* __restrict__ A2, const float* __restrict__ A3,
        const float* __restrict__ A4, const float* __restrict__ A5,
        const float* __restrict__ A6, const float* __restrict__ A7,
        unsigned short* __restrict__ Acat) {
    int b = blockIdx.x;
    const float* src; int gb;   // group base block (16-row units)
    if      (b < 256)  { src = A0; gb = 0;    }
    else if (b < 384)  { src = A1; gb = 256;  }
    else if (b < 448)  { src = A2; gb = 384;  }
    else if (b < 960)  { src = A3; gb = 448;  }
    else if (b < 992)  { src = A4; gb = 960;  }
    else if (b < 1184) { src = A5; gb = 992;  }
    else if (b < 1568) { src = A6; gb = 1184; }
    else               { src = A7; gb = 1568; }
    const float* s    = src  + (long)(b - gb) * 16 * K_DIM;
    unsigned short* d = Acat + (long)b * 16 * K_DIM;
    int t = threadIdx.x;
#pragma unroll 4
    for (int i = 0; i < 16; ++i) {
        long off = (long)i * K_DIM + t * 8;
        float4 x = *(const float4*)(s + off);
        float4 y = *(const float4*)(s + off + 4);
        ushort8 o;
        o[0] = f2bf(x.x); o[1] = f2bf(x.y); o[2] = f2bf(x.z); o[3] = f2bf(x.w);
        o[4] = f2bf(y.x); o[5] = f2bf(y.y); o[6] = f2bf(y.z); o[7] = f2bf(y.w);
        *(ushort8*)(d + off) = o;
    }
}

// ---------- kernel 2: B [K][N] fp32 -> Bt [N][K] bf16 (transpose + convert) ----------
__global__ __launch_bounds__(256) void cvt_bt_kernel(const float* __restrict__ B,
                                                     unsigned short* __restrict__ Bt) {
    __shared__ float t[32][33];
    int bx = blockIdx.x, by = blockIdx.y;
    int tx = threadIdx.x, ty = threadIdx.y;
#pragma unroll
    for (int i = 0; i < 32; i += 8)
        t[ty + i][tx] = B[(long)(by * 32 + ty + i) * N_DIM + bx * 32 + tx];
    __syncthreads();
#pragma unroll
    for (int i = 0; i < 32; i += 8)
        Bt[(long)(bx * 32 + ty + i) * K_DIM + by * 32 + tx] = f2bf(t[tx][ty + i]);
}

// ---------- kernel 3: 256x256 8-phase bf16 GEMM + 128-row M-split tail ----------
// C[M][N] fp32 = Acat[M][K] bf16 * Bt[N][K]^T bf16.  BK=64, 8 waves (2Mx4N),
// 128 KiB LDS double buffer, raw s_barrier, counted vmcnt(6), XOR-swizzled LDS.
// Blocks 0..767: full 256x256 tiles. Blocks 768..863: 128x256 half-tiles of the
// 48 last-scheduled tiles (tail-quantization fix; full K, no reduction needed).

#define PBAR() __builtin_amdgcn_s_barrier()
#define VMC(n)  asm volatile("s_waitcnt vmcnt(" #n ")" ::: "memory")

#define ST_A(BUF, H, L, TT)                                                        \
    __builtin_amdgcn_global_load_lds(                                              \
        GLB(aSt + (long)((H) * 128 + (L) * 64) * K_DIM + (TT) * 64),               \
        LDSP(lds + (BUF) * 32768 + (H) * 8192 + (L) * 4096 + w * 512), 16, 0, 0)
#define ST_B(BUF, H, L, TT)                                                        \
    __builtin_amdgcn_global_load_lds(                                              \
        GLB(bSt + (long)((H) * 128 + (L) * 64) * K_DIM + (TT) * 64),               \
        LDSP(lds + (BUF) * 32768 + 16384 + (H) * 8192 + (L) * 4096 + w * 512), 16, 0, 0)

#define MMQ(MH, NH, AV, BV)                                                        \
    _Pragma("unroll") for (int i = 0; i < 4; ++i)                                  \
    _Pragma("unroll") for (int j = 0; j < 2; ++j)                                  \
        acc[(MH) * 4 + i][(NH) * 2 + j] = __builtin_amdgcn_mfma_f32_16x16x32_bf16( \
            AV[i], BV[j], acc[(MH) * 4 + i][(NH) * 2 + j], 0, 0, 0);

// main tile: no explicit lgkmcnt — ds_reads are IR loads, compiler inserts
// fine-grained lgkmcnt before first MFMA use (m97 behavior).
#define TILE(BUF, T, DO1, DO2)                                                          \
    do {                                                                                \
        const unsigned short* pA = lds + (BUF) * 32768 + wm * 1024 + r16 * 64;          \
        const unsigned short* pB = lds + (BUF) * 32768 + 16384 + wn * 1024 + r16 * 64;  \
        short8 a0[4], a1[4], b00[2], b01[2], b10[2], b11[2];                            \
        /* ph1: read A-h0 + B-h0; stage A(T+1)-h1 -> buf^1; MFMA m0n0 */                \
        _Pragma("unroll") for (int i = 0; i < 4; ++i) {                                 \
            a0[i] = *(const short8*)(pA + i * 2048 + c0 * 8);                           \
            a1[i] = *(const short8*)(pA + i * 2048 + c1 * 8);                           \
        }                                                                               \
        _Pragma("unroll") for (int j = 0; j < 2; ++j) {                                 \
            b00[j] = *(const short8*)(pB + j * 4096 + c0 * 8);                          \
            b01[j] = *(const short8*)(pB + j * 4096 + c1 * 8);                          \
        }                                                                               \
        if (DO1) { ST_A((BUF) ^ 1, 1, 0, (T) + 1); ST_A((BUF) ^ 1, 1, 1, (T) + 1); }    \
        PBAR();                                                                         \
        __builtin_amdgcn_s_setprio(1); MMQ(0, 0, a0, b00); MMQ(0, 0, a1, b01);          \
        __builtin_amdgcn_s_setprio(0); PBAR();                                          \
        /* ph2: read B-h1; stage A(T+2)-h0 -> buf; MFMA m0n1 */                         \
        _Pragma("unroll") for (int j = 0; j < 2; ++j) {                                 \
            b10[j] = *(const short8*)(pB + 8192 + j * 4096 + c0 * 8);                   \
            b11[j] = *(const short8*)(pB + 8192 + j * 4096 + c1 * 8);                   \
        }                                                                               \
        if (DO2) { ST_A((BUF), 0, 0, (T) + 2); ST_A((BUF), 0, 1, (T) + 2); }            \
        PBAR();                                                                         \
        __builtin_amdgcn_s_setprio(1); MMQ(0, 1, a0, b10); MMQ(0, 1, a1, b11);          \
        __builtin_amdgcn_s_setprio(0); PBAR();                                          \
        /* ph3: read A-h1; stage B(T+2)-h0 -> buf; MFMA m1n0 */                         \
        _Pragma("unroll") for (int i = 0; i < 4; ++i) {                                 \
            a0[i] = *(const short8*)(pA + 8192 + i * 2048 + c0 * 8);                    \
            a1[i] = *(const short8*)(pA + 8192 + i * 2048 + c1 * 8);                    \
        }                                                                               \
        if (DO2) { ST_B((BUF), 0, 0, (T) + 2); ST_B((BUF), 0, 1, (T) + 2); }            \
        PBAR();                                                                         \
        __builtin_amdgcn_s_setprio(1); MMQ(1, 0, a0, b00); MMQ(1, 0, a1, b01);          \
        __builtin_amdgcn_s_setprio(0); PBAR();                                          \
        /* ph4: register-only; stage B(T+2)-h1 -> buf; MFMA m1n1 */                     \
        if (DO2) { ST_B((BUF), 1, 0, (T) + 2); ST_B((BUF), 1, 1, (T) + 2); }            \
        __builtin_amdgcn_s_setprio(1); MMQ(1, 1, a0, b10); MMQ(1, 1, a1, b11);          \
        __builtin_amdgcn_s_setprio(0);                                                  \
    } while (0)

// ---- 128-row tail tile: 6 loads/tile, stage T+2 (B-h0@ph3, B-h1+A@ph4) ----
// Region safety: A last ds_read ph3 -> A stage ph4 (1 barrier after ph3-end);
// B-h0 last read ph1 -> stage ph3; B-h1 last read ph2 -> stage ph4.
#define ST_A1(BUF, L, TT)                                                          \
    __builtin_amdgcn_global_load_lds(                                              \
        GLB(aSt + (long)((L) * 64) * K_DIM + (TT) * 64),                           \
        LDSP(lds + (BUF) * 8192 + (L) * 4096 + w * 512), 16, 0, 0)
#define ST_B1(BUF, H, L, TT)                                                       \
    __builtin_amdgcn_global_load_lds(                                              \
        GLB(bSt + (long)((H) * 128 + (L) * 64) * K_DIM + (TT) * 64),               \
        LDSP(lds + 16384 + (BUF) * 16384 + (H) * 8192 + (L) * 4096 + w * 512), 16, 0, 0)

#define MMQ1(MH, NH, AV, BV)                                                       \
    _Pragma("unroll") for (int i = 0; i < 2; ++i)                                  \
    _Pragma("unroll") for (int j = 0; j < 2; ++j)                                  \
        acc[(MH) * 2 + i][(NH) * 2 + j] = __builtin_amdgcn_mfma_f32_16x16x32_bf16( \
            AV[i], BV[j], acc[(MH) * 2 + i][(NH) * 2 + j], 0, 0, 0);

#define TILE128(BUF, T, DO2)                                                            \
    do {                                                                                \
        const unsigned short* pA = lds + (BUF) * 8192 + wm * 1024 + r16 * 64;           \
        const unsigned short* pB = lds + 16384 + (BUF) * 16384 + wn * 1024 + r16 * 64;  \
        short8 a0[2], a1[2], b00[2], b01[2], b10[2], b11[2];                            \
        /* ph1: read A i01 + B j01; MFMA */                                             \
        _Pragma("unroll") for (int i = 0; i < 2; ++i) {                                 \
            a0[i] = *(const short8*)(pA + i * 2048 + c0 * 8);                           \
            a1[i] = *(const short8*)(pA + i * 2048 + c1 * 8);                           \
        }                                                                               \
        _Pragma("unroll") for (int j = 0; j < 2; ++j) {                                 \
            b00[j] = *(const short8*)(pB + j * 4096 + c0 * 8);                          \
            b01[j] = *(const short8*)(pB + j * 4096 + c1 * 8);                          \
        }                                                                               \
        PBAR();                                                                         \
        __builtin_amdgcn_s_setprio(1); MMQ1(0, 0, a0, b00); MMQ1(0, 0, a1, b01);        \
        __builtin_amdgcn_s_setprio(0); PBAR();                                          \
        /* ph2: read B j23; MFMA */                                                     \
        _Pragma("unroll") for (int j = 0; j < 2; ++j) {                                 \
            b10[j] = *(const short8*)(pB + 8192 + j * 4096 + c0 * 8);                   \
            b11[j] = *(const short8*)(pB + 8192 + j * 4096 + c1 * 8);                   \
        }                                                                               \
        PBAR();                                                                         \
        __builtin_amdgcn_s_setprio(1); MMQ1(0, 1, a0, b10); MMQ1(0, 1, a1, b11);        \
        __builtin_amdgcn_s_setprio(0); PBAR();                                          \
        /* ph3: read A i23; stage B(T+2)-h0; MFMA */                                    \
        _Pragma("unroll") for (int i = 0; i < 2; ++i) {                                 \
            a0[i] = *(const short8*)(pA + 4096 + i * 2048 + c0 * 8);                    \
            a1[i] = *(const short8*)(pA + 4096 + i * 2048 + c1 * 8);                    \
        }                                                                               \
        if (DO2) { ST_B1((BUF), 0, 0, (T) + 2); ST_B1((BUF), 0, 1, (T) + 2); }          \
        PBAR();                                                                         \
        __builtin_amdgcn_s_setprio(1); MMQ1(1, 0, a0, b00); MMQ1(1, 0, a1, b01);        \
        __builtin_amdgcn_s_setprio(0); PBAR();                                          \
        /* ph4: stage B(T+2)-h1 + A(T+2); MFMA (register-only) */                       \
        if (DO2) { ST_B1((BUF), 1, 0, (T) + 2); ST_B1((BUF), 1, 1, (T) + 2);            \
                   ST_A1((BUF), 0, (T) + 2);    ST_A1((BUF), 1, (T) + 2); }             \
        __builtin_amdgcn_s_setprio(1); MMQ1(1, 1, a0, b10); MMQ1(1, 1, a1, b11);        \
        __builtin_amdgcn_s_setprio(0);                                                  \
    } while (0)

__global__ __launch_bounds__(512, 2) void gemm8_kernel(const unsigned short* __restrict__ Acat,
                                                       const unsigned short* __restrict__ Bt,
                                                       float* __restrict__ C) {
    __shared__ unsigned short lds[65536];   // 128 KiB

    int wg  = blockIdx.x;
    int tid = threadIdx.x;
    int l   = tid & 63;
    int w   = tid >> 6;          // wave 0..7
    int wm  = w >> 2;            // 0..1
    int wn  = w & 3;             // 0..3
    int r16 = l & 15, kq = l >> 4, x = l & 7;
    int c0  = kq ^ x;            // swizzled chunk, k-step 0
    int c1  = (4 + kq) ^ x;      // swizzled chunk, k-step 1
    int srow = tid >> 3;
    int sq   = (tid & 7) ^ (srow & 7);

    if (wg < 768) {
        // ---------- full 256x256 tile ----------
        int swz = (wg & 7) * 102 + (wg >> 3);
        int mt  = swz >> 3, nt = swz & 7;
        int m0  = mt * 256, n0 = nt * 256;

        const unsigned short* aSt = Acat + (long)(m0 + srow) * K_DIM + sq * 8;
        const unsigned short* bSt = Bt   + (long)(n0 + srow) * K_DIM + sq * 8;

        f32x4 acc[8][4] = {};

        ST_A(0, 0, 0, 0); ST_A(0, 0, 1, 0); ST_A(0, 1, 0, 0); ST_A(0, 1, 1, 0);
        ST_B(0, 0, 0, 0); ST_B(0, 0, 1, 0); ST_B(0, 1, 0, 0); ST_B(0, 1, 1, 0);
        ST_A(1, 0, 0, 1); ST_A(1, 0, 1, 1);
        ST_B(1, 0, 0, 1); ST_B(1, 0, 1, 1); ST_B(1, 1, 0, 1); ST_B(1, 1, 1, 1);
        VMC(6); PBAR();

#pragma unroll 1
        for (int t = 0; t < 30; t += 2) {
            TILE(0, t, 1, 1);     VMC(6); PBAR();
            TILE(1, t + 1, 1, 1); VMC(6); PBAR();
        }
        TILE(0, 30, 1, 0); VMC(0); PBAR();
        TILE(1, 31, 0, 0);

        int orow = m0 + wm * 16 + (l >> 4) * 4;
        int ocol = n0 + wn * 16 + (l & 15);
#pragma unroll
        for (int i = 0; i < 8; ++i)
#pragma unroll
            for (int j = 0; j < 4; ++j)
#pragma unroll
                for (int q = 0; q < 4; ++q)
                    C[(long)(orow + i * 32 + q) * N_DIM + (ocol + j * 64)] = acc[i][j][q];
    } else {
        // ---------- 128x256 half-tile (tail M-split) ----------
        int k    = wg - 768;                 // 0..95
        int o    = 768 + (k >> 1);           // original tile id 768..815
        int half = k & 1;
        int swz  = (o & 7) * 102 + (o >> 3);
        int mt   = swz >> 3, nt = swz & 7;
        int m0   = mt * 256 + half * 128, n0 = nt * 256;

        const unsigned short* aSt = Acat + (long)(m0 + srow) * K_DIM + sq * 8;
        const unsigned short* bSt = Bt   + (long)(n0 + srow) * K_DIM + sq * 8;

        f32x4 acc[4][4] = {};

        // prologue: T0 (6) + T1 (6); vmcnt(6) -> T0 complete
        ST_A1(0, 0, 0); ST_A1(0, 1, 0);
        ST_B1(0, 0, 0, 0); ST_B1(0, 0, 1, 0); ST_B1(0, 1, 0, 0); ST_B1(0, 1, 1, 0);
        ST_A1(1, 0, 1); ST_A1(1, 1, 1);
        ST_B1(1, 0, 0, 1); ST_B1(1, 0, 1, 1); ST_B1(1, 1, 0, 1); ST_B1(1, 1, 1, 1);
        VMC(6); PBAR();

#pragma unroll 1
        for (int t = 0; t < 30; ++t) {
            TILE128(t & 1, t, 1); VMC(6); PBAR();
        }
        TILE128(0, 30, 0); VMC(0); PBAR();
        TILE128(1, 31, 0);

        int orow = m0 + wm * 16 + (l >> 4) * 4;
        int ocol = n0 + wn * 16 + (l & 15);
#pragma unroll
        for (int i = 0; i < 4; ++i)
#pragma unroll
            for (int j = 0; j < 4; ++j)
#pragma unroll
                for (int q = 0; q < 4; ++q)
                    C[(long)(orow + i * 32 + q) * N_DIM + (ocol + j * 64)] = acc[i][j][q];
    }
}

// ---------- fallback: correct (slow) fp32 tiled GEMM, used only if ws too small ----------
__global__ void naive_gemm_kernel(const float* __restrict__ A, const float* __restrict__ B,
                                  float* __restrict__ C, int M) {
    __shared__ float As[16][16];
    __shared__ float Bs[16][17];
    int tx = threadIdx.x, ty = threadIdx.y;
    int row = blockIdx.y * 16 + ty;
    int col = blockIdx.x * 16 + tx;
    float s = 0.f;
    for (int k0 = 0; k0 < K_DIM; k0 += 16) {
        As[ty][tx] = A[(long)row * K_DIM + k0 + tx];
        Bs[ty][tx] = B[(long)(k0 + ty) * N_DIM + col];
        __syncthreads();
#pragma unroll
        for (int t = 0; t < 16; ++t) s += As[ty][t] * Bs[t][tx];
        __syncthreads();
    }
    C[(long)row * N_DIM + col] = s;
}

// ---------- host launcher ----------
extern "C" void kernel_launch(void* const* d_in, const int* in_sizes, int n_in,
                              void* d_out, int out_size, void* d_ws, size_t ws_size,
                              hipStream_t stream) {
    static const int g_m[N_GROUPS]   = {4096, 2048, 1024, 8192, 512, 3072, 6144, 1024};
    static const int g_off[N_GROUPS] = {0, 4096, 6144, 7168, 15360, 15872, 18944, 25088};

    float* C = (float*)d_out;
    const size_t need = ((size_t)M_TOTAL * K_DIM + (size_t)N_DIM * K_DIM) * 2;

    if (ws_size >= need) {
        unsigned short* Acat = (unsigned short*)d_ws;
        unsigned short* Bt   = Acat + (size_t)M_TOTAL * K_DIM;

        cvt_a_all<<<M_TOTAL / 16, 256, 0, stream>>>(
            (const float*)d_in[0], (const float*)d_in[1], (const float*)d_in[2],
            (const float*)d_in[3], (const float*)d_in[4], (const float*)d_in[5],
            (const float*)d_in[6], (const float*)d_in[7], Acat);
        cvt_bt_kernel<<<dim3(N_DIM / 32, K_DIM / 32), dim3(32, 8), 0, stream>>>(
            (const float*)d_in[8], Bt);

        gemm8_kernel<<<768 + 96, 512, 0, stream>>>(Acat, Bt, C);
    } else {
        for (int g = 0; g < N_GROUPS; ++g)
            naive_gemm_kernel<<<dim3(N_DIM / 16, g_m[g] / 16), dim3(16, 16), 0, stream>>>(
                (const float*)d_in[g], (const float*)d_in[8], C + (size_t)g_off[g] * N_DIM,
                g_m[g]);
    }
}

// Round 10
// 280.936 us; speedup vs baseline: 1.5457x; 1.0039x over previous
//
#include <hip/hip_runtime.h>
#include <hip/hip_bf16.h>

// ---------- types ----------
using short8  = __attribute__((ext_vector_type(8))) short;
using ushort8 = __attribute__((ext_vector_type(8))) unsigned short;
using f32x4   = __attribute__((ext_vector_type(4))) float;

#define GLB(p)  ((const __attribute__((address_space(1))) void*)(p))
#define LDSP(p) ((__attribute__((address_space(3))) void*)(p))

static __device__ __forceinline__ unsigned short f2bf(float f) {
    union { float f; unsigned u; } v; v.f = f;
    unsigned u = v.u;
    u += 0x7fffu + ((u >> 16) & 1u);   // round-to-nearest-even
    return (unsigned short)(u >> 16);
}

// ---------- problem constants ----------
#define K_DIM 2048
#define N_DIM 2048
#define M_TOTAL 26112
#define N_GROUPS 8

// ---------- kernel 1: all A groups fp32 -> contiguous bf16 Acat ----------
__global__ __launch_bounds__(256) void cvt_a_all(
        const float* __restrict__ A0, const float* __restrict__ A1,
        const float* __restrict__ A2, const float* __restrict__ A3,
        const float* __restrict__ A4, const float* __restrict__ A5,
        const float* __restrict__ A6, const float* __restrict__ A7,
        unsigned short* __restrict__ Acat) {
    int b = blockIdx.x;
    const float* src; int gb;   // group base block (16-row units)
    if      (b < 256)  { src = A0; gb = 0;    }
    else if (b < 384)  { src = A1; gb = 256;  }
    else if (b < 448)  { src = A2; gb = 384;  }
    else if (b < 960)  { src = A3; gb = 448;  }
    else if (b < 992)  { src = A4; gb = 960;  }
    else if (b < 1184) { src = A5; gb = 992;  }
    else if (b < 1568) { src = A6; gb = 1184; }
    else               { src = A7; gb = 1568; }
    const float* s    = src  + (long)(b - gb) * 16 * K_DIM;
    unsigned short* d = Acat + (long)b * 16 * K_DIM;
    int t = threadIdx.x;
#pragma unroll 4
    for (int i = 0; i < 16; ++i) {
        long off = (long)i * K_DIM + t * 8;
        float4 x = *(const float4*)(s + off);
        float4 y = *(const float4*)(s + off + 4);
        ushort8 o;
        o[0] = f2bf(x.x); o[1] = f2bf(x.y); o[2] = f2bf(x.z); o[3] = f2bf(x.w);
        o[4] = f2bf(y.x); o[5] = f2bf(y.y); o[6] = f2bf(y.z); o[7] = f2bf(y.w);
        *(ushort8*)(d + off) = o;
    }
}

// ---------- kernel 2: B [K][N] fp32 -> Bt [N][K] bf16 (transpose + convert) ----------
__global__ __launch_bounds__(256) void cvt_bt_kernel(const float* __restrict__ B,
                                                     unsigned short* __restrict__ Bt) {
    __shared__ float t[32][33];
    int bx = blockIdx.x, by = blockIdx.y;
    int tx = threadIdx.x, ty = threadIdx.y;
#pragma unroll
    for (int i = 0; i < 32; i += 8)
        t[ty + i][tx] = B[(long)(by * 32 + ty + i) * N_DIM + bx * 32 + tx];
    __syncthreads();
#pragma unroll
    for (int i = 0; i < 32; i += 8)
        Bt[(long)(bx * 32 + ty + i) * K_DIM + by * 32 + tx] = f2bf(t[tx][ty + i]);
}

// ---------- kernel 3: 256x256 8-phase bf16 GEMM + 64-row quarter-tile tail ----------
// C[M][N] fp32 = Acat[M][K] bf16 * Bt[N][K]^T bf16.  BK=64, 8 waves (2Mx4N),
// 128 KiB LDS double buffer, raw s_barrier, counted vmcnt, XOR-swizzled LDS.
// Blocks 0..767: full 256x256 tiles (= exactly 3 dispatch waves on 256 CUs).
// Blocks 768..959: 64x256 quarter-tiles of the 48 last-scheduled tiles
// (critical path 3.5 -> ~3.3 tile-units; full K, no reduction needed).

#define PBAR() __builtin_amdgcn_s_barrier()
#define VMC(n)  asm volatile("s_waitcnt vmcnt(" #n ")" ::: "memory")

#define ST_A(BUF, H, L, TT)                                                        \
    __builtin_amdgcn_global_load_lds(                                              \
        GLB(aSt + (long)((H) * 128 + (L) * 64) * K_DIM + (TT) * 64),               \
        LDSP(lds + (BUF) * 32768 + (H) * 8192 + (L) * 4096 + w * 512), 16, 0, 0)
#define ST_B(BUF, H, L, TT)                                                        \
    __builtin_amdgcn_global_load_lds(                                              \
        GLB(bSt + (long)((H) * 128 + (L) * 64) * K_DIM + (TT) * 64),               \
        LDSP(lds + (BUF) * 32768 + 16384 + (H) * 8192 + (L) * 4096 + w * 512), 16, 0, 0)

#define MMQ(MH, NH, AV, BV)                                                        \
    _Pragma("unroll") for (int i = 0; i < 4; ++i)                                  \
    _Pragma("unroll") for (int j = 0; j < 2; ++j)                                  \
        acc[(MH) * 4 + i][(NH) * 2 + j] = __builtin_amdgcn_mfma_f32_16x16x32_bf16( \
            AV[i], BV[j], acc[(MH) * 4 + i][(NH) * 2 + j], 0, 0, 0);

// full tile (proven round-8 structure, verbatim)
#define TILE(BUF, T, DO1, DO2)                                                          \
    do {                                                                                \
        const unsigned short* pA = lds + (BUF) * 32768 + wm * 1024 + r16 * 64;          \
        const unsigned short* pB = lds + (BUF) * 32768 + 16384 + wn * 1024 + r16 * 64;  \
        short8 a0[4], a1[4], b00[2], b01[2], b10[2], b11[2];                            \
        /* ph1: read A-h0 + B-h0; stage A(T+1)-h1 -> buf^1; MFMA m0n0 */                \
        _Pragma("unroll") for (int i = 0; i < 4; ++i) {                                 \
            a0[i] = *(const short8*)(pA + i * 2048 + c0 * 8);                           \
            a1[i] = *(const short8*)(pA + i * 2048 + c1 * 8);                           \
        }                                                                               \
        _Pragma("unroll") for (int j = 0; j < 2; ++j) {                                 \
            b00[j] = *(const short8*)(pB + j * 4096 + c0 * 8);                          \
            b01[j] = *(const short8*)(pB + j * 4096 + c1 * 8);                          \
        }                                                                               \
        if (DO1) { ST_A((BUF) ^ 1, 1, 0, (T) + 1); ST_A((BUF) ^ 1, 1, 1, (T) + 1); }    \
        PBAR();                                                                         \
        __builtin_amdgcn_s_setprio(1); MMQ(0, 0, a0, b00); MMQ(0, 0, a1, b01);          \
        __builtin_amdgcn_s_setprio(0); PBAR();                                          \
        /* ph2: read B-h1; stage A(T+2)-h0 -> buf; MFMA m0n1 */                         \
        _Pragma("unroll") for (int j = 0; j < 2; ++j) {                                 \
            b10[j] = *(const short8*)(pB + 8192 + j * 4096 + c0 * 8);                   \
            b11[j] = *(const short8*)(pB + 8192 + j * 4096 + c1 * 8);                   \
        }                                                                               \
        if (DO2) { ST_A((BUF), 0, 0, (T) + 2); ST_A((BUF), 0, 1, (T) + 2); }            \
        PBAR();                                                                         \
        __builtin_amdgcn_s_setprio(1); MMQ(0, 1, a0, b10); MMQ(0, 1, a1, b11);          \
        __builtin_amdgcn_s_setprio(0); PBAR();                                          \
        /* ph3: read A-h1; stage B(T+2)-h0 -> buf; MFMA m1n0 */                         \
        _Pragma("unroll") for (int i = 0; i < 4; ++i) {                                 \
            a0[i] = *(const short8*)(pA + 8192 + i * 2048 + c0 * 8);                    \
            a1[i] = *(const short8*)(pA + 8192 + i * 2048 + c1 * 8);                    \
        }                                                                               \
        if (DO2) { ST_B((BUF), 0, 0, (T) + 2); ST_B((BUF), 0, 1, (T) + 2); }            \
        PBAR();                                                                         \
        __builtin_amdgcn_s_setprio(1); MMQ(1, 0, a0, b00); MMQ(1, 0, a1, b01);          \
        __builtin_amdgcn_s_setprio(0); PBAR();                                          \
        /* ph4: register-only; stage B(T+2)-h1 -> buf; MFMA m1n1 */                     \
        if (DO2) { ST_B((BUF), 1, 0, (T) + 2); ST_B((BUF), 1, 1, (T) + 2); }            \
        __builtin_amdgcn_s_setprio(1); MMQ(1, 1, a0, b10); MMQ(1, 1, a1, b11);          \
        __builtin_amdgcn_s_setprio(0);                                                  \
    } while (0)

// ---- 64-row quarter tile: LDS = A 2x4096 shorts @0, B 2x16384 shorts @8192 ----
// 5 loads/tile: B-h0 (ph3), B-h1 + A (ph4).  Region gaps: B-h0 read ph1 / staged
// ph3; B-h1 read ph2 / staged ph4; A read ph1 / staged ph4.  vmcnt(5) per tile.
#define ST_A4(BUF, TT)                                                             \
    __builtin_amdgcn_global_load_lds(                                              \
        GLB(aSt + (long)(TT) * 64),                                                \
        LDSP(lds + (BUF) * 4096 + w * 512), 16, 0, 0)
#define ST_B4(BUF, H, L, TT)                                                       \
    __builtin_amdgcn_global_load_lds(                                              \
        GLB(bSt + (long)((H) * 128 + (L) * 64) * K_DIM + (TT) * 64),               \
        LDSP(lds + 8192 + (BUF) * 16384 + (H) * 8192 + (L) * 4096 + w * 512), 16, 0, 0)

#define MMQ4(NH, AV, BV)                                                           \
    _Pragma("unroll") for (int i = 0; i < 2; ++i)                                  \
    _Pragma("unroll") for (int j = 0; j < 2; ++j)                                  \
        acc[i][(NH) * 2 + j] = __builtin_amdgcn_mfma_f32_16x16x32_bf16(            \
            AV[i], BV[j], acc[i][(NH) * 2 + j], 0, 0, 0);

#define TILE64(BUF, T, DO2)                                                             \
    do {                                                                                \
        const unsigned short* pA = lds + (BUF) * 4096 + wm * 1024 + r16 * 64;           \
        const unsigned short* pB = lds + 8192 + (BUF) * 16384 + wn * 1024 + r16 * 64;   \
        short8 a0[2], a1[2], b00[2], b01[2], b10[2], b11[2];                            \
        /* ph1: read A (both m-frags, both k-steps) + B-h0 (both k-steps); MFMA */      \
        _Pragma("unroll") for (int i = 0; i < 2; ++i) {                                 \
            a0[i] = *(const short8*)(pA + i * 2048 + c0 * 8);                           \
            a1[i] = *(const short8*)(pA + i * 2048 + c1 * 8);                           \
        }                                                                               \
        _Pragma("unroll") for (int j = 0; j < 2; ++j) {                                 \
            b00[j] = *(const short8*)(pB + j * 4096 + c0 * 8);                          \
            b01[j] = *(const short8*)(pB + j * 4096 + c1 * 8);                          \
        }                                                                               \
        PBAR();                                                                         \
        __builtin_amdgcn_s_setprio(1); MMQ4(0, a0, b00);                                \
        __builtin_amdgcn_s_setprio(0); PBAR();                                          \
        /* ph2: read B-h1 (both k-steps); MFMA k-step1 x j01 */                         \
        _Pragma("unroll") for (int j = 0; j < 2; ++j) {                                 \
            b10[j] = *(const short8*)(pB + 8192 + j * 4096 + c0 * 8);                   \
            b11[j] = *(const short8*)(pB + 8192 + j * 4096 + c1 * 8);                   \
        }                                                                               \
        PBAR();                                                                         \
        __builtin_amdgcn_s_setprio(1); MMQ4(0, a1, b01);                                \
        __builtin_amdgcn_s_setprio(0); PBAR();                                          \
        /* ph3: stage B(T+2)-h0; MFMA k-step0 x j23 */                                  \
        if (DO2) { ST_B4((BUF), 0, 0, (T) + 2); ST_B4((BUF), 0, 1, (T) + 2); }          \
        PBAR();                                                                         \
        __builtin_amdgcn_s_setprio(1); MMQ4(1, a0, b10);                                \
        __builtin_amdgcn_s_setprio(0); PBAR();                                          \
        /* ph4: stage B(T+2)-h1 + A(T+2); MFMA k-step1 x j23 */                         \
        if (DO2) { ST_B4((BUF), 1, 0, (T) + 2); ST_B4((BUF), 1, 1, (T) + 2);            \
                   ST_A4((BUF), (T) + 2); }                                             \
        __builtin_amdgcn_s_setprio(1); MMQ4(1, a1, b11);                                \
        __builtin_amdgcn_s_setprio(0);                                                  \
    } while (0)

__global__ __launch_bounds__(512, 2) void gemm8_kernel(const unsigned short* __restrict__ Acat,
                                                       const unsigned short* __restrict__ Bt,
                                                       float* __restrict__ C) {
    __shared__ unsigned short lds[65536];   // 128 KiB

    int wg  = blockIdx.x;
    int tid = threadIdx.x;
    int l   = tid & 63;
    int w   = tid >> 6;          // wave 0..7
    int wm  = w >> 2;            // 0..1
    int wn  = w & 3;             // 0..3
    int r16 = l & 15, kq = l >> 4, x = l & 7;
    int c0  = kq ^ x;            // swizzled chunk, k-step 0
    int c1  = (4 + kq) ^ x;      // swizzled chunk, k-step 1
    int srow = tid >> 3;
    int sq   = (tid & 7) ^ (srow & 7);

    if (wg < 768) {
        // ---------- full 256x256 tile ----------
        int swz = (wg & 7) * 102 + (wg >> 3);
        int mt  = swz >> 3, nt = swz & 7;
        int m0  = mt * 256, n0 = nt * 256;

        const unsigned short* aSt = Acat + (long)(m0 + srow) * K_DIM + sq * 8;
        const unsigned short* bSt = Bt   + (long)(n0 + srow) * K_DIM + sq * 8;

        f32x4 acc[8][4] = {};

        ST_A(0, 0, 0, 0); ST_A(0, 0, 1, 0); ST_A(0, 1, 0, 0); ST_A(0, 1, 1, 0);
        ST_B(0, 0, 0, 0); ST_B(0, 0, 1, 0); ST_B(0, 1, 0, 0); ST_B(0, 1, 1, 0);
        ST_A(1, 0, 0, 1); ST_A(1, 0, 1, 1);
        ST_B(1, 0, 0, 1); ST_B(1, 0, 1, 1); ST_B(1, 1, 0, 1); ST_B(1, 1, 1, 1);
        VMC(6); PBAR();

#pragma unroll 1
        for (int t = 0; t < 30; t += 2) {
            TILE(0, t, 1, 1);     VMC(6); PBAR();
            TILE(1, t + 1, 1, 1); VMC(6); PBAR();
        }
        TILE(0, 30, 1, 0); VMC(0); PBAR();
        TILE(1, 31, 0, 0);

        int orow = m0 + wm * 16 + (l >> 4) * 4;
        int ocol = n0 + wn * 16 + (l & 15);
#pragma unroll
        for (int i = 0; i < 8; ++i)
#pragma unroll
            for (int j = 0; j < 4; ++j)
#pragma unroll
                for (int q = 0; q < 4; ++q)
                    C[(long)(orow + i * 32 + q) * N_DIM + (ocol + j * 64)] = acc[i][j][q];
    } else {
        // ---------- 64x256 quarter-tile (tail M-split x4) ----------
        int k    = wg - 768;                 // 0..191
        int o    = 768 + (k >> 2);           // original tile id 768..815
        int qh   = k & 3;
        int swz  = (o & 7) * 102 + (o >> 3);
        int mt   = swz >> 3, nt = swz & 7;
        int m0   = mt * 256 + qh * 64, n0 = nt * 256;

        const unsigned short* aSt = Acat + (long)(m0 + srow) * K_DIM + sq * 8;
        const unsigned short* bSt = Bt   + (long)(n0 + srow) * K_DIM + sq * 8;

        f32x4 acc[2][4] = {};

        // prologue: T0 (5) + T1 (5); vmcnt(5) -> T0 complete
        ST_A4(0, 0);
        ST_B4(0, 0, 0, 0); ST_B4(0, 0, 1, 0); ST_B4(0, 1, 0, 0); ST_B4(0, 1, 1, 0);
        ST_A4(1, 1);
        ST_B4(1, 0, 0, 1); ST_B4(1, 0, 1, 1); ST_B4(1, 1, 0, 1); ST_B4(1, 1, 1, 1);
        VMC(5); PBAR();

#pragma unroll 1
        for (int t = 0; t < 30; ++t) {
            TILE64(t & 1, t, 1); VMC(5); PBAR();
        }
        TILE64(0, 30, 0); VMC(0); PBAR();
        TILE64(1, 31, 0);

        int orow = m0 + wm * 16 + (l >> 4) * 4;
        int ocol = n0 + wn * 16 + (l & 15);
#pragma unroll
        for (int i = 0; i < 2; ++i)
#pragma unroll
            for (int j = 0; j < 4; ++j)
#pragma unroll
                for (int q = 0; q < 4; ++q)
                    C[(long)(orow + i * 32 + q) * N_DIM + (ocol + j * 64)] = acc[i][j][q];
    }
}

// ---------- fallback: correct (slow) fp32 tiled GEMM, used only if ws too small ----------
__global__ void naive_gemm_kernel(const float* __restrict__ A, const float* __restrict__ B,
                                  float* __restrict__ C, int M) {
    __shared__ float As[16][16];
    __shared__ float Bs[16][17];
    int tx = threadIdx.x, ty = threadIdx.y;
    int row = blockIdx.y * 16 + ty;
    int col = blockIdx.x * 16 + tx;
    float s = 0.f;
    for (int k0 = 0; k0 < K_DIM; k0 += 16) {
        As[ty][tx] = A[(long)row * K_DIM + k0 + tx];
        Bs[ty][tx] = B[(long)(k0 + ty) * N_DIM + col];
        __syncthreads();
#pragma unroll
        for (int t = 0; t < 16; ++t) s += As[ty][t] * Bs[t][tx];
        __syncthreads();
    }
    C[(long)row * N_DIM + col] = s;
}

// ---------- host launcher ----------
extern "C" void kernel_launch(void* const* d_in, const int* in_sizes, int n_in,
                              void* d_out, int out_size, void* d_ws, size_t ws_size,
                              hipStream_t stream) {
    static const int g_m[N_GROUPS]   = {4096, 2048, 1024, 8192, 512, 3072, 6144, 1024};
    static const int g_off[N_GROUPS] = {0, 4096, 6144, 7168, 15360, 15872, 18944, 25088};

    float* C = (float*)d_out;
    const size_t need = ((size_t)M_TOTAL * K_DIM + (size_t)N_DIM * K_DIM) * 2;

    if (ws_size >= need) {
        unsigned short* Acat = (unsigned short*)d_ws;
        unsigned short* Bt   = Acat + (size_t)M_TOTAL * K_DIM;

        cvt_a_all<<<M_TOTAL / 16, 256, 0, stream>>>(
            (const float*)d_in[0], (const float*)d_in[1], (const float*)d_in[2],
            (const float*)d_in[3], (const float*)d_in[4], (const float*)d_in[5],
            (const float*)d_in[6], (const float*)d_in[7], Acat);
        cvt_bt_kernel<<<dim3(N_DIM / 32, K_DIM / 32), dim3(32, 8), 0, stream>>>(
            (const float*)d_in[8], Bt);

        gemm8_kernel<<<768 + 192, 512, 0, stream>>>(Acat, Bt, C);
    } else {
        for (int g = 0; g < N_GROUPS; ++g)
            naive_gemm_kernel<<<dim3(N_DIM / 16, g_m[g] / 16), dim3(16, 16), 0, stream>>>(
                (const float*)d_in[g], (const float*)d_in[8], C + (size_t)g_off[g] * N_DIM,
                g_m[g]);
    }
}